// Round 3
// baseline (249.555 us; speedup 1.0000x reference)
//
#include <hip/hip_runtime.h>
#include <math.h>

#define NXC 200   // grid edge
#define NBB 512   // batch
#define TPB 1024  // threads per block
#define NW  16    // waves per block

// One block (1024 threads = 16 waves) per batch. Wave w owns rows
// i = w + 16k (k=0..12, wave-uniform guard i<200). Lane l<50 loads float4
// covering columns 4l..4l+3.
//
// vs the 68.7us baseline:
//  - row-sum shuffle chain cut 6 -> 2 (+32,+16); 16 comb partials/row go to
//    LDS and are finished after the loop (removes 4 serial lgkm hops/iter).
//  - depth-2 software prefetch via NAMED float4 registers (hA<-hN rotation,
//    no indexed arrays -> cannot go to scratch; round-2 lesson).
//  - no boundary captures in the hot loop; the 8 boundary rows/cols are
//    re-read from global post-loop (L2-hot, ~3KB/block; verified in round 2).
//  - __launch_bounds__(1024,8) pins VGPR<=64 so 2 blocks/CU is guaranteed.
__global__ __launch_bounds__(TPB, 8) void heat_loss_kernel(
    const float* __restrict__ layout, const float* __restrict__ heat,
    float* __restrict__ out) {
  const int b    = blockIdx.x;
  const int tid  = threadIdx.x;
  const int wave = tid >> 6;
  const int lane = tid & 63;
  const bool act = (lane < 50);

  const float4* __restrict__ hp =
      reinterpret_cast<const float4*>(heat + (size_t)b * NXC * NXC);
  const float4* __restrict__ lp =
      reinterpret_cast<const float4*>(layout + (size_t)b * NXC * NXC);

  __shared__ float s_hc[NW][NXC];   // per-wave column partials (heat)
  __shared__ float s_lc[NW][NXC];   // (layout)
  __shared__ float s_ph[NXC][16];   // 16 row-sum comb partials per row (heat)
  __shared__ float s_pl[NXC][16];   // (layout)
  __shared__ float s_CS[NXC];       // total column sums (heat)
  __shared__ float s_CL[NXC];       // (layout)
  __shared__ float s_RS[NXC];       // row sums (heat)
  __shared__ float s_RL[NXC];       // row sums (layout)
  __shared__ float s_red[4][NW];    // minv/maxv/minh/maxh per wave
  __shared__ float s_sum[NW];       // contrib partial per wave

  float hc0=0.f,hc1=0.f,hc2=0.f,hc3=0.f;
  float lc0=0.f,lc1=0.f,lc2=0.f,lc3=0.f;

  // prefetch row k=0
  float4 hA = make_float4(0.f,0.f,0.f,0.f);
  float4 lA = make_float4(0.f,0.f,0.f,0.f);
  if (act) {
    hA = hp[wave * 50 + lane];
    lA = lp[wave * 50 + lane];
  }

  #pragma unroll
  for (int k = 0; k < 13; ++k) {
    const int i = wave + NW * k;            // wave-uniform

    // issue next row's loads before consuming current (depth-2 pipeline)
    float4 hN = make_float4(0.f,0.f,0.f,0.f);
    float4 lN = make_float4(0.f,0.f,0.f,0.f);
    const int in = wave + NW * (k + 1);
    if (k < 12 && in < NXC && act) {
      hN = hp[in * 50 + lane];
      lN = lp[in * 50 + lane];
    }

    if (i < NXC) {
      hc0 += hA.x; hc1 += hA.y; hc2 += hA.z; hc3 += hA.w;
      lc0 += lA.x; lc1 += lA.y; lc2 += lA.z; lc3 += lA.w;

      // 2-deep comb reduce: lanes 0..15 hold stride-16 partials; inactive
      // lanes contributed zeros, so sum over p=0..15 equals the row sum.
      float hs = (hA.x + hA.y) + (hA.z + hA.w);
      float ls = (lA.x + lA.y) + (lA.z + lA.w);
      hs += __shfl_down(hs, 32); ls += __shfl_down(ls, 32);
      hs += __shfl_down(hs, 16); ls += __shfl_down(ls, 16);
      if (lane < 16) { s_ph[i][lane] = hs; s_pl[i][lane] = ls; }
    }
    hA = hN; lA = lN;
  }

  if (act) {
    s_hc[wave][4*lane+0] = hc0; s_hc[wave][4*lane+1] = hc1;
    s_hc[wave][4*lane+2] = hc2; s_hc[wave][4*lane+3] = hc3;
    s_lc[wave][4*lane+0] = lc0; s_lc[wave][4*lane+1] = lc1;
    s_lc[wave][4*lane+2] = lc2; s_lc[wave][4*lane+3] = lc3;
  }
  __syncthreads();

  if (tid < NXC) {
    float a = 0.f, c = 0.f, rh = 0.f, rl = 0.f;
    #pragma unroll
    for (int w = 0; w < NW; ++w) { a += s_hc[w][tid]; c += s_lc[w][tid]; }
    #pragma unroll
    for (int p = 0; p < 16; ++p) { rh += s_ph[tid][p]; rl += s_pl[tid][p]; }
    s_CS[tid] = a; s_CL[tid] = c; s_RS[tid] = rh; s_RL[tid] = rl;
  }
  __syncthreads();

  const float* __restrict__ hb = heat + (size_t)b * NXC * NXC;
  const float COF = (float)(0.25 * (0.1/199.0) * (0.1/199.0));
  float dv = 0.f, dh = 0.f;
  if (tid < NXC) {
    const int j  = tid;
    const int jm = (j == 0) ? 1 : j - 1;
    const int jp = (j == NXC-1) ? NXC-2 : j + 1;

    // boundary rows 0,1,198,199 (coalesced, L2-hot re-reads)
    const float h0   = hb[0*NXC + j];
    const float h1   = hb[1*NXC + j];
    const float h198 = hb[198*NXC + j];
    const float h199 = hb[199*NXC + j];
    float Sv = 0.25f * (2.f*s_CS[j]
                        + h1 - h199        // +h[1,j]   - h[199,j]
                        + h198 - h0        // +h[198,j] - h[0,j]
                        + s_CS[jm] + s_CS[jp])
             + COF * s_CL[j];
    dv = fabsf(Sv - s_CS[j]) * (1.f / NXC);

    // boundary cols 0,1,198,199 of row j via two aligned float4 loads
    const float4 c03 = *reinterpret_cast<const float4*>(hb + (size_t)j*NXC);
    const float4 c69 = *reinterpret_cast<const float4*>(hb + (size_t)j*NXC + 196);
    float Sh = 0.25f * (2.f*s_RS[j]
                        + c03.y - c69.w    // +h[j,1]   - h[j,199]
                        + c69.z - c03.x    // +h[j,198] - h[j,0]
                        + s_RS[jm] + s_RS[jp])
             + COF * s_RL[j];
    dh = fabsf(Sh - s_RS[j]) * (1.f / NXC);
  }

  // per-batch min/max of dv and dh (dv,dh >= 0 so max pad 0 is safe)
  float mnv = (tid < NXC) ? dv : INFINITY;
  float mxv = dv;
  float mnh = (tid < NXC) ? dh : INFINITY;
  float mxh = dh;
  #pragma unroll
  for (int off = 32; off > 0; off >>= 1) {
    mnv = fminf(mnv, __shfl_down(mnv, off));
    mxv = fmaxf(mxv, __shfl_down(mxv, off));
    mnh = fminf(mnh, __shfl_down(mnh, off));
    mxh = fmaxf(mxh, __shfl_down(mxh, off));
  }
  if (lane == 0) {
    s_red[0][wave] = mnv;
    s_red[1][wave] = mxv;
    s_red[2][wave] = mnh;
    s_red[3][wave] = mxh;
  }
  __syncthreads();

  float MNV = INFINITY, MXV = -INFINITY, MNH = INFINITY, MXH = -INFINITY;
  #pragma unroll
  for (int w = 0; w < NW; ++w) {
    MNV = fminf(MNV, s_red[0][w]); MXV = fmaxf(MXV, s_red[1][w]);
    MNH = fminf(MNH, s_red[2][w]); MXH = fmaxf(MXH, s_red[3][w]);
  }

  float contrib = 0.f;
  if (tid < NXC) {
    contrib = 10.f * (dv - MNV) * dv / (MXV - MNV)
            + 10.f * (dh - MNH) * dh / (MXH - MNH);
  }
  #pragma unroll
  for (int off = 32; off > 0; off >>= 1) contrib += __shfl_down(contrib, off);
  if (lane == 0) s_sum[wave] = contrib;
  __syncthreads();
  if (tid == 0) {
    float tot = 0.f;
    #pragma unroll
    for (int w = 0; w < NW; ++w) tot += s_sum[w];
    atomicAdd(out, tot * (1.f / ((float)NBB * (float)NXC)));
  }
}

extern "C" void kernel_launch(void* const* d_in, const int* in_sizes, int n_in,
                              void* d_out, int out_size, void* d_ws, size_t ws_size,
                              hipStream_t stream) {
  const float* layout = (const float*)d_in[0];
  const float* heat   = (const float*)d_in[1];
  float* out = (float*)d_out;

  // d_out is poisoned to 0xAA before every timed launch — zero it first.
  hipMemsetAsync(out, 0, (size_t)out_size * sizeof(float), stream);
  heat_loss_kernel<<<NBB, TPB, 0, stream>>>(layout, heat, out);
}

// Round 4
// 228.733 us; speedup vs baseline: 1.0910x; 1.0910x over previous
//
#include <hip/hip_runtime.h>
#include <math.h>

#define NXC 200   // grid edge
#define NBB 512   // batch
#define TPB 512   // threads per block (8 waves)
#define WPB 8     // waves per block
#define ITER 25   // rows per wave: i = wave + 8*k, k=0..24 (199 max -> NO guards)
#define PADP 17   // padded stride for row-partial arrays (kills bank conflicts)

// One block per batch, 8 waves. Wave w owns rows i = w + 8k (exactly 25 each,
// no guard divergence). Lane l<50 loads float4 covering columns 4l..4l+3.
//
// Spill-proof depth-4 software pipeline: named float4 registers hA..hD/lA..lD,
// hand-rotated (SSA-renamed under full unroll) -- no indexed arrays (round-2
// lesson), no tight launch bounds (round-3 lesson: (1024,8) -> VGPR=32 ->
// 200MB scratch). __launch_bounds__(512,4) allows up to 128 VGPRs: 32 data
// regs in flight + accumulators fit with slack.
//
// Row sums: 2 shuffle-adds in-loop (vs baseline's 6 serial lgkm hops); lanes
// 0..15 store stride-16 comb partials to LDS, finished after the loop.
// Column sums accumulate per-lane in registers. Boundary rows/cols re-read
// from global post-loop (L2-hot, ~3KB/block; exactness verified rounds 1-3).
// Zero workspace -> no extra HBM traffic (round-1 lesson).
__global__ __launch_bounds__(TPB, 4) void heat_loss_kernel(
    const float* __restrict__ layout, const float* __restrict__ heat,
    float* __restrict__ out) {
  const int b    = blockIdx.x;
  const int tid  = threadIdx.x;
  const int wave = tid >> 6;
  const int lane = tid & 63;
  const bool act = (lane < 50);

  const float4* __restrict__ hp =
      reinterpret_cast<const float4*>(heat + (size_t)b * NXC * NXC);
  const float4* __restrict__ lp =
      reinterpret_cast<const float4*>(layout + (size_t)b * NXC * NXC);

  __shared__ float s_hc[WPB][NXC];   // per-wave column partials (heat)
  __shared__ float s_lc[WPB][NXC];   // (layout)
  __shared__ float s_ph[NXC][PADP];  // 16 row-sum comb partials per row (heat)
  __shared__ float s_pl[NXC][PADP];  // (layout)
  __shared__ float s_CS[NXC];        // total column sums (heat)
  __shared__ float s_CL[NXC];        // (layout)
  __shared__ float s_RS[NXC];        // row sums (heat)
  __shared__ float s_RL[NXC];        // row sums (layout)
  __shared__ float s_red[4][WPB];    // minv/maxv/minh/maxh per wave
  __shared__ float s_sum[WPB];       // contrib partial per wave

  float hc0=0.f,hc1=0.f,hc2=0.f,hc3=0.f;
  float lc0=0.f,lc1=0.f,lc2=0.f,lc3=0.f;

  const float4 Z = make_float4(0.f,0.f,0.f,0.f);
  float4 hA=Z,hB=Z,hC=Z,hD=Z;
  float4 lA=Z,lB=Z,lC=Z,lD=Z;

  // prologue: rows k=0..3 in flight (inactive lanes stay zero forever)
  if (act) {
    const int base = wave * 50 + lane;
    hA = hp[base +    0]; lA = lp[base +    0];   // row wave
    hB = hp[base +  400]; lB = lp[base +  400];   // row wave+8
    hC = hp[base +  800]; lC = lp[base +  800];   // row wave+16
    hD = hp[base + 1200]; lD = lp[base + 1200];   // row wave+24
  }

  #pragma unroll
  for (int k = 0; k < ITER; ++k) {
    const float4 hv = hA;
    const float4 lv = lA;
    // rotate pipeline (copies are renamed away under full unroll)
    hA = hB; hB = hC; hC = hD;
    lA = lB; lB = lC; lC = lD;
    if (k + 4 < ITER) {
      if (act) {
        const int idx = (wave + 8 * (k + 4)) * 50 + lane;
        hD = hp[idx];
        lD = lp[idx];
      }
    } else {
      hD = Z; lD = Z;
    }

    const int i = wave + 8 * k;            // wave-uniform, always < 200
    hc0 += hv.x; hc1 += hv.y; hc2 += hv.z; hc3 += hv.w;
    lc0 += lv.x; lc1 += lv.y; lc2 += lv.z; lc3 += lv.w;

    // 2-deep comb reduce: lanes 0..15 hold stride-16 partials; lanes >=50
    // carry zeros, so the sum over p=0..15 equals the full row sum.
    float hs = (hv.x + hv.y) + (hv.z + hv.w);
    float ls = (lv.x + lv.y) + (lv.z + lv.w);
    hs += __shfl_down(hs, 32); ls += __shfl_down(ls, 32);
    hs += __shfl_down(hs, 16); ls += __shfl_down(ls, 16);
    if (lane < 16) { s_ph[i][lane] = hs; s_pl[i][lane] = ls; }
  }

  if (act) {
    s_hc[wave][4*lane+0] = hc0; s_hc[wave][4*lane+1] = hc1;
    s_hc[wave][4*lane+2] = hc2; s_hc[wave][4*lane+3] = hc3;
    s_lc[wave][4*lane+0] = lc0; s_lc[wave][4*lane+1] = lc1;
    s_lc[wave][4*lane+2] = lc2; s_lc[wave][4*lane+3] = lc3;
  }
  __syncthreads();

  if (tid < NXC) {
    float a = 0.f, c = 0.f, rh = 0.f, rl = 0.f;
    #pragma unroll
    for (int w = 0; w < WPB; ++w) { a += s_hc[w][tid]; c += s_lc[w][tid]; }
    #pragma unroll
    for (int p = 0; p < 16; ++p) { rh += s_ph[tid][p]; rl += s_pl[tid][p]; }
    s_CS[tid] = a; s_CL[tid] = c; s_RS[tid] = rh; s_RL[tid] = rl;
  }
  __syncthreads();

  const float* __restrict__ hb = heat + (size_t)b * NXC * NXC;
  const float COF = (float)(0.25 * (0.1/199.0) * (0.1/199.0));
  float dv = 0.f, dh = 0.f;
  if (tid < NXC) {
    const int j  = tid;
    const int jm = (j == 0) ? 1 : j - 1;
    const int jp = (j == NXC-1) ? NXC-2 : j + 1;

    // boundary rows 0,1,198,199 (coalesced, L2-hot re-reads)
    const float h0   = hb[0*NXC + j];
    const float h1   = hb[1*NXC + j];
    const float h198 = hb[198*NXC + j];
    const float h199 = hb[199*NXC + j];
    float Sv = 0.25f * (2.f*s_CS[j]
                        + h1 - h199        // +h[1,j]   - h[199,j]
                        + h198 - h0        // +h[198,j] - h[0,j]
                        + s_CS[jm] + s_CS[jp])
             + COF * s_CL[j];
    dv = fabsf(Sv - s_CS[j]) * (1.f / NXC);

    // boundary cols 0,1,198,199 of row j via two aligned float4 loads
    const float4 c03 = *reinterpret_cast<const float4*>(hb + (size_t)j*NXC);
    const float4 c69 = *reinterpret_cast<const float4*>(hb + (size_t)j*NXC + 196);
    float Sh = 0.25f * (2.f*s_RS[j]
                        + c03.y - c69.w    // +h[j,1]   - h[j,199]
                        + c69.z - c03.x    // +h[j,198] - h[j,0]
                        + s_RS[jm] + s_RS[jp])
             + COF * s_RL[j];
    dh = fabsf(Sh - s_RS[j]) * (1.f / NXC);
  }

  // per-batch min/max of dv and dh (dv,dh >= 0 so max pad 0 is safe)
  float mnv = (tid < NXC) ? dv : INFINITY;
  float mxv = dv;
  float mnh = (tid < NXC) ? dh : INFINITY;
  float mxh = dh;
  #pragma unroll
  for (int off = 32; off > 0; off >>= 1) {
    mnv = fminf(mnv, __shfl_down(mnv, off));
    mxv = fmaxf(mxv, __shfl_down(mxv, off));
    mnh = fminf(mnh, __shfl_down(mnh, off));
    mxh = fmaxf(mxh, __shfl_down(mxh, off));
  }
  if (lane == 0) {
    s_red[0][wave] = mnv;
    s_red[1][wave] = mxv;
    s_red[2][wave] = mnh;
    s_red[3][wave] = mxh;
  }
  __syncthreads();

  float MNV = INFINITY, MXV = -INFINITY, MNH = INFINITY, MXH = -INFINITY;
  #pragma unroll
  for (int w = 0; w < WPB; ++w) {
    MNV = fminf(MNV, s_red[0][w]); MXV = fmaxf(MXV, s_red[1][w]);
    MNH = fminf(MNH, s_red[2][w]); MXH = fmaxf(MXH, s_red[3][w]);
  }

  float contrib = 0.f;
  if (tid < NXC) {
    contrib = 10.f * (dv - MNV) * dv / (MXV - MNV)
            + 10.f * (dh - MNH) * dh / (MXH - MNH);
  }
  #pragma unroll
  for (int off = 32; off > 0; off >>= 1) contrib += __shfl_down(contrib, off);
  if (lane == 0) s_sum[wave] = contrib;
  __syncthreads();
  if (tid == 0) {
    float tot = 0.f;
    #pragma unroll
    for (int w = 0; w < WPB; ++w) tot += s_sum[w];
    atomicAdd(out, tot * (1.f / ((float)NBB * (float)NXC)));
  }
}

extern "C" void kernel_launch(void* const* d_in, const int* in_sizes, int n_in,
                              void* d_out, int out_size, void* d_ws, size_t ws_size,
                              hipStream_t stream) {
  const float* layout = (const float*)d_in[0];
  const float* heat   = (const float*)d_in[1];
  float* out = (float*)d_out;

  // d_out is poisoned to 0xAA before every timed launch — zero it first.
  hipMemsetAsync(out, 0, (size_t)out_size * sizeof(float), stream);
  heat_loss_kernel<<<NBB, TPB, 0, stream>>>(layout, heat, out);
}

// Round 5
// 188.632 us; speedup vs baseline: 1.3230x; 1.2126x over previous
//
#include <hip/hip_runtime.h>
#include <math.h>

#define NXC 200   // grid edge
#define NBB 512   // batch
#define RC  32    // rows per full chunk
#define NCH 7     // 6 full chunks + 1 tail chunk (8 rows)
#define CHF (RC * NXC)        // floats per chunk buffer (6400)
#define CHB (CHF * 4)         // bytes per full chunk (25600)

#define GAS(p) ((const __attribute__((address_space(1))) void*)(p))
#define LAS(p) ((__attribute__((address_space(3))) void*)(p))

// Stage one array-chunk into LDS via async DMA (global_load_lds).
// Full chunk: 25600 B = 25 x (64 lanes x 16 B) width-16 ops, spread over waves.
// Tail chunk: 6400 B = 6 x 1KB width-16 + 1 x 256 B width-4.
// LDS dest is wave-uniform base + lane*size (m104) -> flat row-major layout.
__device__ __forceinline__ void stage(const char* gsrc, char* lds,
                                      int rows, int wave, int lane) {
  if (rows == RC) {
    #pragma unroll
    for (int t0 = 0; t0 < 2; ++t0) {
      const int t = wave + 16 * t0;            // wave-uniform
      if (t < 25) {
        __builtin_amdgcn_global_load_lds(GAS(gsrc + t * 1024 + lane * 16),
                                         LAS(lds + t * 1024), 16, 0, 0);
      }
    }
  } else {  // 8-row tail: 6400 B
    if (wave < 6) {
      __builtin_amdgcn_global_load_lds(GAS(gsrc + wave * 1024 + lane * 16),
                                       LAS(lds + wave * 1024), 16, 0, 0);
    }
    if (wave == 15) {
      __builtin_amdgcn_global_load_lds(GAS(gsrc + 6144 + lane * 4),
                                       LAS(lds + 6144), 4, 0, 0);
    }
  }
}

// One block (1024 threads, 16 waves) per batch. Double-buffered async LDS
// staging: issue chunk c+1's DMA, compute sums on chunk c from LDS, then
// __syncthreads (compiler emits vmcnt(0) drain before s_barrier -> chunk c+1
// complete). Zero data VGPRs in the staging path -> cannot spill (rounds 2-4
// lesson). Full 64-lane 16B staging ops (baseline wasted 14/64 lanes).
// Compute phase uses disjoint thread groups concurrently:
//   tid 0..199    : heat column sums   (scalar LDS walk, conflict-free)
//   tid 256..383  : heat row sums      (4 threads/row, float4 LDS reads)
//   tid 512..711  : layout column sums
//   tid 768..895  : layout row sums
// Boundary rows/cols re-read from global post-loop (L2-hot, verified r1-r4).
__global__ __launch_bounds__(1024) void heat_loss_kernel(
    const float* __restrict__ layout, const float* __restrict__ heat,
    float* __restrict__ out) {
  const int b    = blockIdx.x;
  const int tid  = threadIdx.x;
  const int wave = tid >> 6;
  const int lane = tid & 63;

  __shared__ __align__(16) float bh[2][CHF];   // heat chunk double-buffer
  __shared__ __align__(16) float bl[2][CHF];   // layout chunk double-buffer
  __shared__ float s_rpH[NXC][4];  // per-row 4 partials (heat)
  __shared__ float s_rpL[NXC][4];  // (layout)
  __shared__ float s_CS[NXC];      // column sums heat
  __shared__ float s_CL[NXC];      // column sums layout
  __shared__ float s_RS[NXC];      // row sums heat
  __shared__ float s_RL[NXC];      // row sums layout
  __shared__ float s_red[4][16];   // minv/maxv/minh/maxh per wave
  __shared__ float s_sum[16];      // contrib partial per wave

  const char* hsrc = (const char*)(heat   + (size_t)b * NXC * NXC);
  const char* lsrc = (const char*)(layout + (size_t)b * NXC * NXC);

  float colAcc = 0.f;  // tid<200: heat col sum; tid in [512,712): layout col sum

  // prologue: stage chunk 0 into buffer 0
  stage(hsrc, (char*)bh[0], RC, wave, lane);
  stage(lsrc, (char*)bl[0], RC, wave, lane);
  __syncthreads();  // drains vmcnt(0) before barrier

  for (int c = 0; c < NCH; ++c) {
    const int cur  = c & 1;
    const int rows = (c < 6) ? RC : 8;

    // issue next chunk's DMA before computing on the current one
    if (c + 1 < NCH) {
      const int nrows = (c + 1 < 6) ? RC : 8;
      stage(hsrc + (size_t)(c + 1) * CHB, (char*)bh[cur ^ 1], nrows, wave, lane);
      stage(lsrc + (size_t)(c + 1) * CHB, (char*)bl[cur ^ 1], nrows, wave, lane);
    }

    // ---- compute on chunk c ----
    const int crow0 = c * RC;
    if (tid < NXC) {
      float a = colAcc;
      for (int r = 0; r < rows; ++r) a += bh[cur][r * NXC + tid];
      colAcc = a;
    } else if (tid >= 256 && tid < 256 + 4 * rows) {
      const int t2 = tid - 256, r = t2 >> 2, s = t2 & 3;
      const float4* rp = (const float4*)&bh[cur][r * NXC];
      float acc = 0.f;
      for (int m = s; m < 50; m += 4) {
        const float4 v = rp[m];
        acc += (v.x + v.y) + (v.z + v.w);
      }
      s_rpH[crow0 + r][s] = acc;
    } else if (tid >= 512 && tid < 512 + NXC) {
      const int j = tid - 512;
      float a = colAcc;
      for (int r = 0; r < rows; ++r) a += bl[cur][r * NXC + j];
      colAcc = a;
    } else if (tid >= 768 && tid < 768 + 4 * rows) {
      const int t2 = tid - 768, r = t2 >> 2, s = t2 & 3;
      const float4* rp = (const float4*)&bl[cur][r * NXC];
      float acc = 0.f;
      for (int m = s; m < 50; m += 4) {
        const float4 v = rp[m];
        acc += (v.x + v.y) + (v.z + v.w);
      }
      s_rpL[crow0 + r][s] = acc;
    }
    __syncthreads();  // vmcnt(0) drain: chunk c+1 staged; buffers safe to reuse
  }

  // fold partials into the final per-batch vectors
  if (tid < NXC) {
    s_CS[tid] = colAcc;
    s_RS[tid] = (s_rpH[tid][0] + s_rpH[tid][1]) + (s_rpH[tid][2] + s_rpH[tid][3]);
    s_RL[tid] = (s_rpL[tid][0] + s_rpL[tid][1]) + (s_rpL[tid][2] + s_rpL[tid][3]);
  } else if (tid >= 512 && tid < 512 + NXC) {
    s_CL[tid - 512] = colAcc;
  }
  __syncthreads();

  const float* __restrict__ hb = heat + (size_t)b * NXC * NXC;
  const float COF = (float)(0.25 * (0.1 / 199.0) * (0.1 / 199.0));
  float dv = 0.f, dh = 0.f;
  if (tid < NXC) {
    const int j  = tid;
    const int jm = (j == 0) ? 1 : j - 1;
    const int jp = (j == NXC - 1) ? NXC - 2 : j + 1;

    // boundary rows 0,1,198,199 (coalesced, L2-hot re-reads; verified r1-r4)
    const float h0   = hb[0 * NXC + j];
    const float h1   = hb[1 * NXC + j];
    const float h198 = hb[198 * NXC + j];
    const float h199 = hb[199 * NXC + j];
    float Sv = 0.25f * (2.f * s_CS[j]
                        + h1 - h199        // +h[1,j]   - h[199,j]
                        + h198 - h0        // +h[198,j] - h[0,j]
                        + s_CS[jm] + s_CS[jp])
             + COF * s_CL[j];
    dv = fabsf(Sv - s_CS[j]) * (1.f / NXC);

    // boundary cols 0,1,198,199 of row j via two aligned float4 loads
    const float4 c03 = *reinterpret_cast<const float4*>(hb + (size_t)j * NXC);
    const float4 c69 = *reinterpret_cast<const float4*>(hb + (size_t)j * NXC + 196);
    float Sh = 0.25f * (2.f * s_RS[j]
                        + c03.y - c69.w    // +h[j,1]   - h[j,199]
                        + c69.z - c03.x    // +h[j,198] - h[j,0]
                        + s_RS[jm] + s_RS[jp])
             + COF * s_RL[j];
    dh = fabsf(Sh - s_RS[j]) * (1.f / NXC);
  }

  // per-batch min/max of dv and dh (dv,dh >= 0 so max pad 0 is safe)
  float mnv = (tid < NXC) ? dv : INFINITY;
  float mxv = dv;
  float mnh = (tid < NXC) ? dh : INFINITY;
  float mxh = dh;
  #pragma unroll
  for (int off = 32; off > 0; off >>= 1) {
    mnv = fminf(mnv, __shfl_down(mnv, off));
    mxv = fmaxf(mxv, __shfl_down(mxv, off));
    mnh = fminf(mnh, __shfl_down(mnh, off));
    mxh = fmaxf(mxh, __shfl_down(mxh, off));
  }
  if (lane == 0) {
    s_red[0][wave] = mnv;
    s_red[1][wave] = mxv;
    s_red[2][wave] = mnh;
    s_red[3][wave] = mxh;
  }
  __syncthreads();

  float MNV = INFINITY, MXV = -INFINITY, MNH = INFINITY, MXH = -INFINITY;
  #pragma unroll
  for (int w = 0; w < 16; ++w) {
    MNV = fminf(MNV, s_red[0][w]); MXV = fmaxf(MXV, s_red[1][w]);
    MNH = fminf(MNH, s_red[2][w]); MXH = fmaxf(MXH, s_red[3][w]);
  }

  float contrib = 0.f;
  if (tid < NXC) {
    contrib = 10.f * (dv - MNV) * dv / (MXV - MNV)
            + 10.f * (dh - MNH) * dh / (MXH - MNH);
  }
  #pragma unroll
  for (int off = 32; off > 0; off >>= 1) contrib += __shfl_down(contrib, off);
  if (lane == 0) s_sum[wave] = contrib;
  __syncthreads();
  if (tid == 0) {
    float tot = 0.f;
    #pragma unroll
    for (int w = 0; w < 16; ++w) tot += s_sum[w];
    atomicAdd(out, tot * (1.f / ((float)NBB * (float)NXC)));
  }
}

extern "C" void kernel_launch(void* const* d_in, const int* in_sizes, int n_in,
                              void* d_out, int out_size, void* d_ws, size_t ws_size,
                              hipStream_t stream) {
  const float* layout = (const float*)d_in[0];
  const float* heat   = (const float*)d_in[1];
  float* out = (float*)d_out;

  // d_out is poisoned to 0xAA before every timed launch — zero it first.
  hipMemsetAsync(out, 0, (size_t)out_size * sizeof(float), stream);
  heat_loss_kernel<<<NBB, 1024, 0, stream>>>(layout, heat, out);
}

// Round 7
// 178.385 us; speedup vs baseline: 1.3990x; 1.0574x over previous
//
#include <hip/hip_runtime.h>
#include <math.h>

#define NXC 200    // grid edge
#define NBB 512    // batch
#define TPB 1024   // threads per block (16 waves)
#define NACT 1000  // active threads in the streaming loop
#define KIT 10     // 1000 threads x 10 iters = 10000 float4 = one full batch

// One block per batch (512 blocks, 2 blocks/CU -> full 2048 threads/CU).
// Streaming-probe structure: the hot loop is the closest legal analog of the
// m13 6.3TB/s float4-copy loop -- 1000/1024 lanes active, NO shuffles, NO
// barriers, NO guards, 10 independent float4 loads per thread per array.
//
// Index algebra (the trick): thread t<1000 reads f = t + 1000k, k=0..9.
//   quad  q = f mod 50 = t mod 50 = c   (static per thread, 1000%50==0)
//   row   r = f div 50 = t/50 + 20k = a + 20k  (static per thread+k)
// -> column sums accumulate in 4 named registers (columns 4c..4c+3);
// -> row partial (quad-sum) of row a+20k, quad c has exactly ONE writer:
//    thread (a,c) at iter k -> plain LDS store, no reduction in the loop.
// Heat and layout are two sequential passes sharing the partial buffers
// (spill-safe: only ~1 float4 + accumulators live; 59KB LDS, 2 blocks/CU).
// Epilogue (boundary re-reads + OHEM) identical to rounds 1-5 (absmax 0).
__global__ __launch_bounds__(TPB) void heat_loss_kernel(
    const float* __restrict__ layout, const float* __restrict__ heat,
    float* __restrict__ out) {
  const int b    = blockIdx.x;
  const int tid  = threadIdx.x;
  const int wave = tid >> 6;
  const int lane = tid & 63;

  __shared__ __align__(16) float4 s_colp[20][50];  // col-quad partials (16 KB)
  __shared__ float s_rowp[NXC][51];  // row-quad partials, pad 51: gcd(19,32)=1
  __shared__ float s_CS[NXC];        // column sums heat
  __shared__ float s_CL[NXC];        // column sums layout
  __shared__ float s_RS[NXC];        // row sums heat
  __shared__ float s_RL[NXC];        // row sums layout
  __shared__ float s_red[4][16];     // minv/maxv/minh/maxh per wave
  __shared__ float s_sum[16];        // contrib partial per wave

  const float4* __restrict__ hp =
      reinterpret_cast<const float4*>(heat + (size_t)b * NXC * NXC);
  const float4* __restrict__ lp =
      reinterpret_cast<const float4*>(layout + (size_t)b * NXC * NXC);

  const int a = tid / 50;   // 0..19 for active threads
  const int c = tid % 50;

  // ---------------- pass 1: heat ----------------
  if (tid < NACT) {
    float cs0 = 0.f, cs1 = 0.f, cs2 = 0.f, cs3 = 0.f;
    #pragma unroll
    for (int k = 0; k < KIT; ++k) {
      const float4 v = hp[tid + NACT * k];
      cs0 += v.x; cs1 += v.y; cs2 += v.z; cs3 += v.w;
      s_rowp[a + 20 * k][c] = (v.x + v.y) + (v.z + v.w);  // single writer
    }
    s_colp[a][c] = make_float4(cs0, cs1, cs2, cs3);
  }
  __syncthreads();

  if (tid < NXC) {
    const float* cp = (const float*)s_colp;  // [a][200] flat view
    float s = 0.f;
    #pragma unroll
    for (int a2 = 0; a2 < 20; ++a2) s += cp[a2 * 200 + tid];
    float r = 0.f;
    #pragma unroll
    for (int m = 0; m < 50; ++m) r += s_rowp[tid][m];
    s_CS[tid] = s; s_RS[tid] = r;
  }
  __syncthreads();  // partial buffers now reusable

  // ---------------- pass 2: layout ----------------
  if (tid < NACT) {
    float cs0 = 0.f, cs1 = 0.f, cs2 = 0.f, cs3 = 0.f;
    #pragma unroll
    for (int k = 0; k < KIT; ++k) {
      const float4 v = lp[tid + NACT * k];
      cs0 += v.x; cs1 += v.y; cs2 += v.z; cs3 += v.w;
      s_rowp[a + 20 * k][c] = (v.x + v.y) + (v.z + v.w);
    }
    s_colp[a][c] = make_float4(cs0, cs1, cs2, cs3);
  }
  __syncthreads();

  if (tid < NXC) {
    const float* cp = (const float*)s_colp;
    float s = 0.f;
    #pragma unroll
    for (int a2 = 0; a2 < 20; ++a2) s += cp[a2 * 200 + tid];
    float r = 0.f;
    #pragma unroll
    for (int m = 0; m < 50; ++m) r += s_rowp[tid][m];
    s_CL[tid] = s; s_RL[tid] = r;
  }
  __syncthreads();

  // ---------------- epilogue (verified exact in rounds 1-5) ----------------
  const float* __restrict__ hb = heat + (size_t)b * NXC * NXC;
  const float COF = (float)(0.25 * (0.1 / 199.0) * (0.1 / 199.0));
  float dv = 0.f, dh = 0.f;
  if (tid < NXC) {
    const int j  = tid;
    const int jm = (j == 0) ? 1 : j - 1;
    const int jp = (j == NXC - 1) ? NXC - 2 : j + 1;

    // boundary rows 0,1,198,199 (coalesced, L2-hot re-reads)
    const float h0   = hb[0 * NXC + j];
    const float h1   = hb[1 * NXC + j];
    const float h198 = hb[198 * NXC + j];
    const float h199 = hb[199 * NXC + j];
    float Sv = 0.25f * (2.f * s_CS[j]
                        + h1 - h199        // +h[1,j]   - h[199,j]
                        + h198 - h0        // +h[198,j] - h[0,j]
                        + s_CS[jm] + s_CS[jp])
             + COF * s_CL[j];
    dv = fabsf(Sv - s_CS[j]) * (1.f / NXC);

    // boundary cols 0,1,198,199 of row j via two aligned float4 loads
    const float4 c03 = *reinterpret_cast<const float4*>(hb + (size_t)j * NXC);
    const float4 c69 = *reinterpret_cast<const float4*>(hb + (size_t)j * NXC + 196);
    float Sh = 0.25f * (2.f * s_RS[j]
                        + c03.y - c69.w    // +h[j,1]   - h[j,199]
                        + c69.z - c03.x    // +h[j,198] - h[j,0]
                        + s_RS[jm] + s_RS[jp])
             + COF * s_RL[j];
    dh = fabsf(Sh - s_RS[j]) * (1.f / NXC);
  }

  // per-batch min/max of dv and dh (dv,dh >= 0 so max pad 0 is safe)
  float mnv = (tid < NXC) ? dv : INFINITY;
  float mxv = dv;
  float mnh = (tid < NXC) ? dh : INFINITY;
  float mxh = dh;
  #pragma unroll
  for (int off = 32; off > 0; off >>= 1) {
    mnv = fminf(mnv, __shfl_down(mnv, off));
    mxv = fmaxf(mxv, __shfl_down(mxv, off));
    mnh = fminf(mnh, __shfl_down(mnh, off));
    mxh = fmaxf(mxh, __shfl_down(mxh, off));
  }
  if (lane == 0) {
    s_red[0][wave] = mnv;
    s_red[1][wave] = mxv;
    s_red[2][wave] = mnh;
    s_red[3][wave] = mxh;
  }
  __syncthreads();

  float MNV = INFINITY, MXV = -INFINITY, MNH = INFINITY, MXH = -INFINITY;
  #pragma unroll
  for (int w = 0; w < 16; ++w) {
    MNV = fminf(MNV, s_red[0][w]); MXV = fmaxf(MXV, s_red[1][w]);
    MNH = fminf(MNH, s_red[2][w]); MXH = fmaxf(MXH, s_red[3][w]);
  }

  float contrib = 0.f;
  if (tid < NXC) {
    contrib = 10.f * (dv - MNV) * dv / (MXV - MNV)
            + 10.f * (dh - MNH) * dh / (MXH - MNH);
  }
  #pragma unroll
  for (int off = 32; off > 0; off >>= 1) contrib += __shfl_down(contrib, off);
  if (lane == 0) s_sum[wave] = contrib;
  __syncthreads();
  if (tid == 0) {
    float tot = 0.f;
    #pragma unroll
    for (int w = 0; w < 16; ++w) tot += s_sum[w];
    atomicAdd(out, tot * (1.f / ((float)NBB * (float)NXC)));
  }
}

extern "C" void kernel_launch(void* const* d_in, const int* in_sizes, int n_in,
                              void* d_out, int out_size, void* d_ws, size_t ws_size,
                              hipStream_t stream) {
  const float* layout = (const float*)d_in[0];
  const float* heat   = (const float*)d_in[1];
  float* out = (float*)d_out;

  // d_out is poisoned to 0xAA before every timed launch — zero it first.
  hipMemsetAsync(out, 0, (size_t)out_size * sizeof(float), stream);
  heat_loss_kernel<<<NBB, TPB, 0, stream>>>(layout, heat, out);
}